// Round 11
// baseline (114.974 us; speedup 1.0000x reference)
//
#include <hip/hip_runtime.h>
#include <hip/hip_bf16.h>
#include <stdint.h>

typedef __bf16 bf16;
typedef __bf16 bf16x8 __attribute__((ext_vector_type(8)));
typedef __bf16 bf16x4 __attribute__((ext_vector_type(4)));
typedef float  f32x4  __attribute__((ext_vector_type(4)));
typedef float  f32x16 __attribute__((ext_vector_type(16)));
typedef unsigned int u32;

#define DM 1024
#define NH 16
#define HD 64
#define TT 2048

// log2(e)/8 : puts QK^T scores directly in exp2 domain
#define QSCALE 0.18033688011112042f

__global__ void cvt_all(const float* __restrict__ x,  const float* __restrict__ wq,
                        const float* __restrict__ wk, const float* __restrict__ wv,
                        const float* __restrict__ wo,
                        bf16* __restrict__ xb,  bf16* __restrict__ wqb,
                        bf16* __restrict__ wkb, bf16* __restrict__ wvb,
                        bf16* __restrict__ wob) {
  const int i = (blockIdx.x * blockDim.x + threadIdx.x) * 4;
  const float* src; bf16* dst; int off;
  if (i < 4194304)      { src = x;  dst = xb;  off = i; }
  else {
    const int j = i - 4194304;
    const int w = j >> 20;
    off = j & 1048575;
    src = (w == 0) ? wq : (w == 1) ? wk : (w == 2) ? wv : wo;
    dst = (w == 0) ? wqb : (w == 1) ? wkb : (w == 2) ? wvb : wob;
  }
  const float4 v = *reinterpret_cast<const float4*>(src + off);
  bf16x4 o = { (bf16)v.x, (bf16)v.y, (bf16)v.z, (bf16)v.w };
  *reinterpret_cast<bf16x4*>(dst + off) = o;
}

static __device__ __forceinline__ void gload_lds16(const bf16* g, bf16* l) {
  __builtin_amdgcn_global_load_lds(
      (__attribute__((address_space(1))) void*)g,
      (__attribute__((address_space(3))) void*)l, 16, 0, 0);
}

// XOR swizzle: spreads the 8 16B-slots of a 128B row across banks by row
static __device__ __forceinline__ int swzb(int lin) {
  return lin ^ (((lin >> 7) & 7) << 4);
}

static __device__ __forceinline__ u32 cvtpk(float lo, float hi) {
  u32 r;
  asm("v_cvt_pk_bf16_f32 %0, %1, %2" : "=v"(r) : "v"(lo), "v"(hi));
  return r;
}
static __device__ __forceinline__ void plswap(u32& a, u32& b) {
  asm("v_permlane32_swap_b32 %0, %1" : "+v"(a), "+v"(b));
}

// ---------------- QKV projection: double-buffered counted-vmcnt K-loop ------
__launch_bounds__(256, 3)
__global__ void gemm_qkv(const bf16* __restrict__ X, const bf16* __restrict__ Wq,
                         const bf16* __restrict__ Wk, const bf16* __restrict__ Wv,
                         bf16* __restrict__ Qb, bf16* __restrict__ Kb,
                         bf16* __restrict__ Vtb) {
  __shared__ bf16 As[2][128 * 32];
  __shared__ bf16 Bs[2][128 * 32];
  const int tid  = threadIdx.x;
  const int lane = tid & 63;
  const int wv   = tid >> 6;
  const int lg   = lane >> 4, lc = lane & 15;
  const int m0   = blockIdx.x * 128;
  const int ng   = blockIdx.y * 128;
  const int which = ng >> 10;                 // 0=Q 1=K 2=V
  const bf16* W = (which == 0) ? Wq : ((which == 1) ? Wk : Wv);
  const int n0 = ng & 1023;
  const int wm = wv >> 1, wn = wv & 1;

  // per-thread staging geometry (constant): 2 issues per matrix per K-step
  int lrow[2], lcol[2], ldst[2];
#pragma unroll
  for (int c = 0; c < 2; ++c) {
    const int e = wv * 512 + c * 2048 + lane * 8;
    lrow[c] = e >> 5; lcol[c] = e & 31; ldst[c] = wv * 512 + c * 2048;
  }

#define QSTAGE(buf, kt)                                                        \
  {                                                                            \
    _Pragma("unroll")                                                          \
    for (int c = 0; c < 2; ++c) {                                              \
      gload_lds16(X + (size_t)(m0 + lrow[c]) * DM + (kt) * 32 + lcol[c],       \
                  &As[buf][ldst[c]]);                                          \
      gload_lds16(W + (size_t)(n0 + lrow[c]) * DM + (kt) * 32 + lcol[c],       \
                  &Bs[buf][ldst[c]]);                                          \
    }                                                                          \
  }

  f32x4 acc[4][4] = {};
  QSTAGE(0, 0);

  int cur = 0;
  for (int kt = 0; kt < 32; ++kt) {
    if (kt + 1 < 32) {
      QSTAGE(cur ^ 1, kt + 1);
      asm volatile("s_waitcnt vmcnt(4)" ::: "memory");   // current step landed
    } else {
      asm volatile("s_waitcnt vmcnt(0)" ::: "memory");
    }
    __builtin_amdgcn_s_barrier();
    __builtin_amdgcn_sched_barrier(0);

    bf16x8 a[4], b[4];
#pragma unroll
    for (int i = 0; i < 4; ++i)
      a[i] = *reinterpret_cast<const bf16x8*>(&As[cur][(wm * 64 + i * 16 + lc) * 32 + lg * 8]);
#pragma unroll
    for (int j = 0; j < 4; ++j)
      b[j] = *reinterpret_cast<const bf16x8*>(&Bs[cur][(wn * 64 + j * 16 + lc) * 32 + lg * 8]);
    __builtin_amdgcn_s_setprio(1);
#pragma unroll
    for (int i = 0; i < 4; ++i)
#pragma unroll
      for (int j = 0; j < 4; ++j)
        acc[i][j] = __builtin_amdgcn_mfma_f32_16x16x32_bf16(a[i], b[j], acc[i][j], 0, 0, 0);
    __builtin_amdgcn_s_setprio(0);

    __builtin_amdgcn_s_barrier();
    cur ^= 1;
  }
#undef QSTAGE

#pragma unroll
  for (int i = 0; i < 4; ++i) {
    const int mg = m0 + wm * 64 + i * 16 + lg * 4;
    const int bb = mg >> 11, t = mg & 2047;
#pragma unroll
    for (int j = 0; j < 4; ++j) {
      const int nl = n0 + wn * 64 + j * 16 + lc;
      const int h = nl >> 6, d = nl & 63;
      const int bh = bb * NH + h;
      const f32x4 v = acc[i][j];
      if (which == 0) {
        bf16* p = Qb + ((size_t)bh * TT + t) * HD + d;
#pragma unroll
        for (int r = 0; r < 4; ++r) p[r * HD] = (bf16)(v[r] * QSCALE);
      } else if (which == 1) {
        bf16* p = Kb + ((size_t)bh * TT + t) * HD + d;
#pragma unroll
        for (int r = 0; r < 4; ++r) p[r * HD] = (bf16)v[r];
      } else {
        bf16x4 pk = { (bf16)v[0], (bf16)v[1], (bf16)v[2], (bf16)v[3] };
        *reinterpret_cast<bf16x4*>(Vtb + ((size_t)bh * HD + d) * TT + t) = pk;
      }
    }
  }
}

// ---------------- flash attention: 32x32 MFMA, in-register P ----------------
// 1024 blocks x 2 waves x 32 q-rows = exactly 4 blocks/CU, ALL resident.
// Balanced static mapping under stride-256 co-residency (bid, bid+256, ...):
// hi=bid>>8, mid=(bid>>5)&7 -> qc = 8*hi + (hi<2 ? mid : 7-mid); every CU's
// four blocks get {mid, 8+mid, 23-mid, 31-mid} = 62 tile-units (was 48..76).
// XCD-grouped bh keeps each XCD's K/V/Q in its 4MB L2. Double-buffered LDS,
// counted vmcnt(8/0). Swapped QK^T 32x32x16, in-register P (T12), T13.
#define MF32(a, b, c) __builtin_amdgcn_mfma_f32_32x32x16_bf16((a), (b), (c), 0, 0, 0)

__launch_bounds__(128, 2)
__global__ void attn_fwd(const bf16* __restrict__ Qb, const bf16* __restrict__ Kb,
                         const bf16* __restrict__ Vtb, bf16* __restrict__ Yb) {
  __shared__ bf16 Ks[2][4096];     // 2 x [64 kv x 64 d] swizzled rows (16 KB)
  __shared__ bf16 Vs[2][4096];     // 2 x [64 d x 64 kv] swizzled rows (16 KB)

  const int tid  = threadIdx.x;
  const int lane = tid & 63;
  const int wv   = tid >> 6;         // 0..1
  const int m31  = lane & 31;
  const int hi   = lane >> 5;
  const int hi16 = hi << 4;
  const int hi4  = hi << 2;
  const int xr   = (m31 & 7) << 4;
  const int kRow = m31 * 128;
  int colx[4];
#pragma unroll
  for (int i = 0; i < 4; ++i) colx[i] = (i * 32 + hi16) ^ xr;

  // balanced static mapping (see header comment)
  const int u    = blockIdx.x & 31;
  const int bh   = ((u & 7) << 2) | (u >> 3);      // XCD-grouped
  const int bhi  = blockIdx.x >> 8;                 // 0..3
  const int bmid = (blockIdx.x >> 5) & 7;           // 0..7
  const int qc   = 8 * bhi + ((bhi < 2) ? bmid : (7 - bmid));
  const int NT   = qc + 1;
  const int qb0  = qc * 64 + wv * 32;
  const int qrow = qb0 + m31;

  const bf16* Qg = Qb  + (size_t)bh * TT * HD;
  const bf16* Kg = Kb  + (size_t)bh * TT * HD;
  const bf16* Vg = Vtb + (size_t)bh * HD * TT;

  // staging offsets: dest linear (wave-uniform base + lane*16), src pre-swizzled
  int dstb[4], koff[4], voff[4];
#pragma unroll
  for (int c = 0; c < 4; ++c) {
    const int base = (wv * 4 + c) * 1024;
    const int lin  = base + lane * 16;
    dstb[c] = base;
    koff[c] = swzb(lin);
    voff[c] = (lin >> 7) * (TT * 2) + (swzb(lin) & 127);
  }

  // Q fragments (B-operand): lane holds q=m31, d = ds*16 + 8*hi + j
  bf16x8 qr0 = *reinterpret_cast<const bf16x8*>(Qg + (size_t)qrow * HD + 0  + hi * 8);
  bf16x8 qr1 = *reinterpret_cast<const bf16x8*>(Qg + (size_t)qrow * HD + 16 + hi * 8);
  bf16x8 qr2 = *reinterpret_cast<const bf16x8*>(Qg + (size_t)qrow * HD + 32 + hi * 8);
  bf16x8 qr3 = *reinterpret_cast<const bf16x8*>(Qg + (size_t)qrow * HD + 48 + hi * 8);

  f32x16 o0 = {}, o1 = {};           // O^T rows d = dsub*32 + crow, col q = m31
  float m_run = -INFINITY, l_run = 0.f;

#define STAGE(buf, kv)                                                          \
  {                                                                             \
    _Pragma("unroll")                                                           \
    for (int c = 0; c < 4; ++c) {                                               \
      gload_lds16((const bf16*)((const char*)Kg + (size_t)(kv) * 8192 + koff[c]), \
                  (bf16*)((char*)Ks[buf] + dstb[c]));                           \
      gload_lds16((const bf16*)((const char*)Vg + (size_t)(kv) * 128 + voff[c]),  \
                  (bf16*)((char*)Vs[buf] + dstb[c]));                           \
    }                                                                           \
  }

  STAGE(0, 0);                       // 8 per-wave loads outstanding

  int cur = 0;
  for (int ti = 0; ti < NT; ++ti) {
    if (ti + 1 < NT) {
      STAGE(cur ^ 1, ti + 1);
      asm volatile("s_waitcnt vmcnt(8)" ::: "memory");    // tile ti landed
    } else {
      asm volatile("s_waitcnt vmcnt(0)" ::: "memory");
    }
    __builtin_amdgcn_s_barrier();
    __builtin_amdgcn_sched_barrier(0);

    const char* ksb = (const char*)Ks[cur];
    const char* vsb = (const char*)Vs[cur];
    const int k0 = ti * 64;

    // ---- QK^T: S^T[kv][q], A = K (m=kv), B = Q (n=q) ----
    f32x16 s0 = {}, s1 = {};
    __builtin_amdgcn_s_setprio(1);
    {
      bf16x8 kf;
      kf = *reinterpret_cast<const bf16x8*>(ksb + kRow + colx[0]); s0 = MF32(kf, qr0, s0);
      kf = *reinterpret_cast<const bf16x8*>(ksb + kRow + colx[1]); s0 = MF32(kf, qr1, s0);
      kf = *reinterpret_cast<const bf16x8*>(ksb + kRow + colx[2]); s0 = MF32(kf, qr2, s0);
      kf = *reinterpret_cast<const bf16x8*>(ksb + kRow + colx[3]); s0 = MF32(kf, qr3, s0);
      kf = *reinterpret_cast<const bf16x8*>(ksb + 4096 + kRow + colx[0]); s1 = MF32(kf, qr0, s1);
      kf = *reinterpret_cast<const bf16x8*>(ksb + 4096 + kRow + colx[1]); s1 = MF32(kf, qr1, s1);
      kf = *reinterpret_cast<const bf16x8*>(ksb + 4096 + kRow + colx[2]); s1 = MF32(kf, qr2, s1);
      kf = *reinterpret_cast<const bf16x8*>(ksb + 4096 + kRow + colx[3]); s1 = MF32(kf, qr3, s1);
    }
    __builtin_amdgcn_s_setprio(0);

    // ---- causal mask (diagonal tile only) ----
    if (k0 + 63 > qb0) {
#pragma unroll
      for (int r = 0; r < 16; ++r) {
        const int kvl = (r & 3) + 8 * (r >> 2) + hi4;
        if (k0 + kvl > qrow)      s0[r] = -INFINITY;
        if (k0 + 32 + kvl > qrow) s1[r] = -INFINITY;
      }
    }

    // ---- row max: in-lane tree + one cross-half exchange ----
    float q0m = fmaxf(fmaxf(s0[0], s0[1]),  fmaxf(s0[2], s0[3]));
    float q1m = fmaxf(fmaxf(s0[4], s0[5]),  fmaxf(s0[6], s0[7]));
    float q2m = fmaxf(fmaxf(s0[8], s0[9]),  fmaxf(s0[10], s0[11]));
    float q3m = fmaxf(fmaxf(s0[12], s0[13]), fmaxf(s0[14], s0[15]));
    float q4m = fmaxf(fmaxf(s1[0], s1[1]),  fmaxf(s1[2], s1[3]));
    float q5m = fmaxf(fmaxf(s1[4], s1[5]),  fmaxf(s1[6], s1[7]));
    float q6m = fmaxf(fmaxf(s1[8], s1[9]),  fmaxf(s1[10], s1[11]));
    float q7m = fmaxf(fmaxf(s1[12], s1[13]), fmaxf(s1[14], s1[15]));
    float pm = fmaxf(fmaxf(fmaxf(q0m, q1m), fmaxf(q2m, q3m)),
                     fmaxf(fmaxf(q4m, q5m), fmaxf(q6m, q7m)));
    pm = fmaxf(pm, __shfl_xor(pm, 32));

    // ---- T13 defer-rescale ----
    const int need = pm > m_run + 8.f;
    if (__any(need)) {
      const float mn = fmaxf(m_run, pm);
      const float al = __builtin_amdgcn_exp2f(m_run - mn);
      m_run = mn; l_run *= al;
#pragma unroll
      for (int r = 0; r < 16; ++r) { o0[r] *= al; o1[r] *= al; }
    }

#pragma unroll
    for (int r = 0; r < 16; ++r) {
      s0[r] = __builtin_amdgcn_exp2f(s0[r] - m_run);
      s1[r] = __builtin_amdgcn_exp2f(s1[r] - m_run);
    }

    // ---- P -> PV B-fragments in registers (cvt_pk + permlane32_swap) ----
    union PU { u32 w[4]; bf16x8 v; } pu0, pu1, pu2, pu3;
    {
      u32 a0 = cvtpk(s0[0],  s0[1]),  a1 = cvtpk(s0[2],  s0[3]);
      u32 b0 = cvtpk(s0[4],  s0[5]),  b1 = cvtpk(s0[6],  s0[7]);
      plswap(a0, b0); plswap(a1, b1);
      pu0.w[0] = a0; pu0.w[1] = a1; pu0.w[2] = b0; pu0.w[3] = b1;
      u32 c0 = cvtpk(s0[8],  s0[9]),  c1 = cvtpk(s0[10], s0[11]);
      u32 d0 = cvtpk(s0[12], s0[13]), d1 = cvtpk(s0[14], s0[15]);
      plswap(c0, d0); plswap(c1, d1);
      pu1.w[0] = c0; pu1.w[1] = c1; pu1.w[2] = d0; pu1.w[3] = d1;
      u32 e0 = cvtpk(s1[0],  s1[1]),  e1 = cvtpk(s1[2],  s1[3]);
      u32 f0 = cvtpk(s1[4],  s1[5]),  f1 = cvtpk(s1[6],  s1[7]);
      plswap(e0, f0); plswap(e1, f1);
      pu2.w[0] = e0; pu2.w[1] = e1; pu2.w[2] = f0; pu2.w[3] = f1;
      u32 g0 = cvtpk(s1[8],  s1[9]),  g1 = cvtpk(s1[10], s1[11]);
      u32 h0 = cvtpk(s1[12], s1[13]), h1 = cvtpk(s1[14], s1[15]);
      plswap(g0, h0); plswap(g1, h1);
      pu3.w[0] = g0; pu3.w[1] = g1; pu3.w[2] = h0; pu3.w[3] = h1;
    }

    // ---- O^T += V^T P : A = V^T (m=d), B = P (n=q) ----
    __builtin_amdgcn_s_setprio(1);
    {
      bf16x8 vf;
      vf = *reinterpret_cast<const bf16x8*>(vsb + kRow + colx[0]);        o0 = MF32(vf, pu0.v, o0);
      vf = *reinterpret_cast<const bf16x8*>(vsb + 4096 + kRow + colx[0]); o1 = MF32(vf, pu0.v, o1);
      vf = *reinterpret_cast<const bf16x8*>(vsb + kRow + colx[1]);        o0 = MF32(vf, pu1.v, o0);
      vf = *reinterpret_cast<const bf16x8*>(vsb + 4096 + kRow + colx[1]); o1 = MF32(vf, pu1.v, o1);
      vf = *reinterpret_cast<const bf16x8*>(vsb + kRow + colx[2]);        o0 = MF32(vf, pu2.v, o0);
      vf = *reinterpret_cast<const bf16x8*>(vsb + 4096 + kRow + colx[2]); o1 = MF32(vf, pu2.v, o1);
      vf = *reinterpret_cast<const bf16x8*>(vsb + kRow + colx[3]);        o0 = MF32(vf, pu3.v, o0);
      vf = *reinterpret_cast<const bf16x8*>(vsb + 4096 + kRow + colx[3]); o1 = MF32(vf, pu3.v, o1);
    }
    __builtin_amdgcn_s_setprio(0);

    // ---- l-sum (off the pre-PV chain) ----
    float u0 = (s0[0] + s0[1]) + (s0[2] + s0[3]);
    float u1 = (s0[4] + s0[5]) + (s0[6] + s0[7]);
    float u2 = (s0[8] + s0[9]) + (s0[10] + s0[11]);
    float u3 = (s0[12] + s0[13]) + (s0[14] + s0[15]);
    float u4 = (s1[0] + s1[1]) + (s1[2] + s1[3]);
    float u5 = (s1[4] + s1[5]) + (s1[6] + s1[7]);
    float u6 = (s1[8] + s1[9]) + (s1[10] + s1[11]);
    float u7 = (s1[12] + s1[13]) + (s1[14] + s1[15]);
    float rsum = ((u0 + u1) + (u2 + u3)) + ((u4 + u5) + (u6 + u7));
    rsum += __shfl_xor(rsum, 32);
    l_run += rsum;

    __builtin_amdgcn_s_barrier();    // all waves done reading buffer `cur`
    cur ^= 1;
  }
#undef STAGE

  // ---- writeback: y[b*T + q][h*64 + d] ----
  {
    const float linv = 1.f / fmaxf(l_run, 1e-9f);
    bf16* yrow = Yb + ((size_t)((bh >> 4) * TT + qrow)) * DM + (bh & 15) * HD;
#pragma unroll
    for (int rq = 0; rq < 4; ++rq) {
      bf16x4 y0 = { (bf16)(o0[rq * 4 + 0] * linv), (bf16)(o0[rq * 4 + 1] * linv),
                    (bf16)(o0[rq * 4 + 2] * linv), (bf16)(o0[rq * 4 + 3] * linv) };
      *reinterpret_cast<bf16x4*>(yrow + rq * 8 + hi4) = y0;
      bf16x4 y1 = { (bf16)(o1[rq * 4 + 0] * linv), (bf16)(o1[rq * 4 + 1] * linv),
                    (bf16)(o1[rq * 4 + 2] * linv), (bf16)(o1[rq * 4 + 3] * linv) };
      *reinterpret_cast<bf16x4*>(yrow + 32 + rq * 8 + hi4) = y1;
    }
  }
}

// ---------------- output projection: double-buffered counted-vmcnt ----------
__launch_bounds__(256, 3)
__global__ void gemm_out(const bf16* __restrict__ Y, const bf16* __restrict__ Wo,
                         float* __restrict__ Out) {
  __shared__ bf16 As[2][64 * 32];
  __shared__ bf16 Bs[2][128 * 32];
  const int tid  = threadIdx.x;
  const int lane = tid & 63;
  const int wv   = tid >> 6;
  const int lg   = lane >> 4, lc = lane & 15;
  const int m0   = blockIdx.x * 64;
  const int n0   = blockIdx.y * 128;
  const int wm = wv >> 1, wn = wv & 1;   // wave tile: 32 rows x 64 cols

  // staging geometry: A = 1 issue/thread, B = 2 issues/thread
  const int ea   = wv * 512 + lane * 8;
  const int arow = ea >> 5, acol = ea & 31, adst = wv * 512;
  int brow[2], bcol[2], bdst[2];
#pragma unroll
  for (int c = 0; c < 2; ++c) {
    const int e = wv * 1024 + c * 512 + lane * 8;
    brow[c] = e >> 5; bcol[c] = e & 31; bdst[c] = wv * 1024 + c * 512;
  }

#define OSTAGE(buf, kt)                                                        \
  {                                                                            \
    gload_lds16(Y + (size_t)(m0 + arow) * DM + (kt) * 32 + acol,               \
                &As[buf][adst]);                                               \
    _Pragma("unroll")                                                          \
    for (int c = 0; c < 2; ++c)                                                \
      gload_lds16(Wo + (size_t)(n0 + brow[c]) * DM + (kt) * 32 + bcol[c],      \
                  &Bs[buf][bdst[c]]);                                          \
  }

  f32x4 acc[2][4] = {};
  OSTAGE(0, 0);

  int cur = 0;
  for (int kt = 0; kt < 32; ++kt) {
    if (kt + 1 < 32) {
      OSTAGE(cur ^ 1, kt + 1);
      asm volatile("s_waitcnt vmcnt(3)" ::: "memory");   // current step landed
    } else {
      asm volatile("s_waitcnt vmcnt(0)" ::: "memory");
    }
    __builtin_amdgcn_s_barrier();
    __builtin_amdgcn_sched_barrier(0);

    bf16x8 a[2], b[4];
#pragma unroll
    for (int i = 0; i < 2; ++i)
      a[i] = *reinterpret_cast<const bf16x8*>(&As[cur][(wm * 32 + i * 16 + lc) * 32 + lg * 8]);
#pragma unroll
    for (int j = 0; j < 4; ++j)
      b[j] = *reinterpret_cast<const bf16x8*>(&Bs[cur][(wn * 64 + j * 16 + lc) * 32 + lg * 8]);
    __builtin_amdgcn_s_setprio(1);
#pragma unroll
    for (int i = 0; i < 2; ++i)
#pragma unroll
      for (int j = 0; j < 4; ++j)
        acc[i][j] = __builtin_amdgcn_mfma_f32_16x16x32_bf16(a[i], b[j], acc[i][j], 0, 0, 0);
    __builtin_amdgcn_s_setprio(0);

    __builtin_amdgcn_s_barrier();
    cur ^= 1;
  }
#undef OSTAGE

#pragma unroll
  for (int i = 0; i < 2; ++i) {
    const int mg = m0 + wm * 32 + i * 16 + lg * 4;
#pragma unroll
    for (int j = 0; j < 4; ++j) {
      const int n = n0 + wn * 64 + j * 16 + lc;
#pragma unroll
      for (int r = 0; r < 4; ++r)
        Out[(size_t)(mg + r) * DM + n] = acc[i][j][r];
    }
  }
}

extern "C" void kernel_launch(void* const* d_in, const int* in_sizes, int n_in,
                              void* d_out, int out_size, void* d_ws, size_t ws_size,
                              hipStream_t stream) {
  const float* x  = (const float*)d_in[0];
  const float* Wq = (const float*)d_in[1];
  const float* Wk = (const float*)d_in[2];
  const float* Wv = (const float*)d_in[3];
  const float* Wo = (const float*)d_in[4];
  float* out = (float*)d_out;
  char* ws = (char*)d_ws;
  const size_t MB = 1024 * 1024;

  bf16* xb  = (bf16*)(ws + 0);        // 8 MB, reused as yb after QKV GEMM
  bf16* wqb = (bf16*)(ws + 8  * MB);
  bf16* wkb = (bf16*)(ws + 10 * MB);
  bf16* wvb = (bf16*)(ws + 12 * MB);
  bf16* wob = (bf16*)(ws + 14 * MB);
  bf16* Qb  = (bf16*)(ws + 16 * MB);  // [32,2048,64]
  bf16* Kb  = (bf16*)(ws + 24 * MB);
  bf16* Vtb = (bf16*)(ws + 32 * MB);  // [32,64,2048]
  bf16* yb  = xb;

  cvt_all<<<8192, 256, 0, stream>>>(x, Wq, Wk, Wv, Wo, xb, wqb, wkb, wvb, wob);
  gemm_qkv<<<dim3(32, 24), 256, 0, stream>>>(xb, wqb, wkb, wvb, Qb, Kb, Vtb);
  attn_fwd<<<1024, 128, 0, stream>>>(Qb, Kb, Vtb, yb);
  gemm_out<<<dim3(64, 8), 256, 0, stream>>>(yb, wob, out);
}

// Round 12
// 103.855 us; speedup vs baseline: 1.1071x; 1.1071x over previous
//
#include <hip/hip_runtime.h>
#include <hip/hip_bf16.h>
#include <stdint.h>

typedef __bf16 bf16;
typedef __bf16 bf16x8 __attribute__((ext_vector_type(8)));
typedef __bf16 bf16x4 __attribute__((ext_vector_type(4)));
typedef float  f32x4  __attribute__((ext_vector_type(4)));

#define DM 1024
#define NH 16
#define HD 64
#define TT 2048

// log2(e)/8 : puts QK^T scores directly in exp2 domain
#define QSCALE 0.18033688011112042f

__global__ void cvt_all(const float* __restrict__ x,  const float* __restrict__ wq,
                        const float* __restrict__ wk, const float* __restrict__ wv,
                        const float* __restrict__ wo,
                        bf16* __restrict__ xb,  bf16* __restrict__ wqb,
                        bf16* __restrict__ wkb, bf16* __restrict__ wvb,
                        bf16* __restrict__ wob) {
  const int i = (blockIdx.x * blockDim.x + threadIdx.x) * 4;
  const float* src; bf16* dst; int off;
  if (i < 4194304)      { src = x;  dst = xb;  off = i; }
  else {
    const int j = i - 4194304;
    const int w = j >> 20;
    off = j & 1048575;
    src = (w == 0) ? wq : (w == 1) ? wk : (w == 2) ? wv : wo;
    dst = (w == 0) ? wqb : (w == 1) ? wkb : (w == 2) ? wvb : wob;
  }
  const float4 v = *reinterpret_cast<const float4*>(src + off);
  bf16x4 o = { (bf16)v.x, (bf16)v.y, (bf16)v.z, (bf16)v.w };
  *reinterpret_cast<bf16x4*>(dst + off) = o;
}

static __device__ __forceinline__ void gload_lds16(const bf16* g, bf16* l) {
  __builtin_amdgcn_global_load_lds(
      (__attribute__((address_space(1))) void*)g,
      (__attribute__((address_space(3))) void*)l, 16, 0, 0);
}

// XOR swizzle for 128B rows: spread the 8 16B-slots across banks by row
static __device__ __forceinline__ int swzb(int lin) {
  return lin ^ (((lin >> 7) & 7) << 4);
}

// ---------------- QKV projection: double-buffered counted-vmcnt K-loop ------
__launch_bounds__(256, 3)
__global__ void gemm_qkv(const bf16* __restrict__ X, const bf16* __restrict__ Wq,
                         const bf16* __restrict__ Wk, const bf16* __restrict__ Wv,
                         bf16* __restrict__ Qb, bf16* __restrict__ Kb,
                         bf16* __restrict__ Vtb) {
  __shared__ bf16 As[2][128 * 32];
  __shared__ bf16 Bs[2][128 * 32];
  const int tid  = threadIdx.x;
  const int lane = tid & 63;
  const int wv   = tid >> 6;
  const int lg   = lane >> 4, lc = lane & 15;
  const int m0   = blockIdx.x * 128;
  const int ng   = blockIdx.y * 128;
  const int which = ng >> 10;                 // 0=Q 1=K 2=V
  const bf16* W = (which == 0) ? Wq : ((which == 1) ? Wk : Wv);
  const int n0 = ng & 1023;
  const int wm = wv >> 1, wn = wv & 1;

  int lrow[2], lcol[2], ldst[2];
#pragma unroll
  for (int c = 0; c < 2; ++c) {
    const int e = wv * 512 + c * 2048 + lane * 8;
    lrow[c] = e >> 5; lcol[c] = e & 31; ldst[c] = wv * 512 + c * 2048;
  }

#define QSTAGE(buf, kt)                                                        \
  {                                                                            \
    _Pragma("unroll")                                                          \
    for (int c = 0; c < 2; ++c) {                                              \
      gload_lds16(X + (size_t)(m0 + lrow[c]) * DM + (kt) * 32 + lcol[c],       \
                  &As[buf][ldst[c]]);                                          \
      gload_lds16(W + (size_t)(n0 + lrow[c]) * DM + (kt) * 32 + lcol[c],       \
                  &Bs[buf][ldst[c]]);                                          \
    }                                                                          \
  }

  f32x4 acc[4][4] = {};
  QSTAGE(0, 0);

  int cur = 0;
  for (int kt = 0; kt < 32; ++kt) {
    if (kt + 1 < 32) {
      QSTAGE(cur ^ 1, kt + 1);
      asm volatile("s_waitcnt vmcnt(4)" ::: "memory");
    } else {
      asm volatile("s_waitcnt vmcnt(0)" ::: "memory");
    }
    __builtin_amdgcn_s_barrier();
    __builtin_amdgcn_sched_barrier(0);

    bf16x8 a[4], b[4];
#pragma unroll
    for (int i = 0; i < 4; ++i)
      a[i] = *reinterpret_cast<const bf16x8*>(&As[cur][(wm * 64 + i * 16 + lc) * 32 + lg * 8]);
#pragma unroll
    for (int j = 0; j < 4; ++j)
      b[j] = *reinterpret_cast<const bf16x8*>(&Bs[cur][(wn * 64 + j * 16 + lc) * 32 + lg * 8]);
    __builtin_amdgcn_s_setprio(1);
#pragma unroll
    for (int i = 0; i < 4; ++i)
#pragma unroll
      for (int j = 0; j < 4; ++j)
        acc[i][j] = __builtin_amdgcn_mfma_f32_16x16x32_bf16(a[i], b[j], acc[i][j], 0, 0, 0);
    __builtin_amdgcn_s_setprio(0);

    __builtin_amdgcn_s_barrier();
    cur ^= 1;
  }
#undef QSTAGE

#pragma unroll
  for (int i = 0; i < 4; ++i) {
    const int mg = m0 + wm * 64 + i * 16 + lg * 4;
    const int bb = mg >> 11, t = mg & 2047;
#pragma unroll
    for (int j = 0; j < 4; ++j) {
      const int nl = n0 + wn * 64 + j * 16 + lc;
      const int h = nl >> 6, d = nl & 63;
      const int bh = bb * NH + h;
      const f32x4 v = acc[i][j];
      if (which == 0) {
        bf16* p = Qb + ((size_t)bh * TT + t) * HD + d;
#pragma unroll
        for (int r = 0; r < 4; ++r) p[r * HD] = (bf16)(v[r] * QSCALE);
      } else if (which == 1) {
        bf16* p = Kb + ((size_t)bh * TT + t) * HD + d;
#pragma unroll
        for (int r = 0; r < 4; ++r) p[r * HD] = (bf16)v[r];
      } else {
        bf16x4 pk = { (bf16)v[0], (bf16)v[1], (bf16)v[2], (bf16)v[3] };
        *reinterpret_cast<bf16x4*>(Vtb + ((size_t)bh * HD + d) * TT + t) = pk;
      }
    }
  }
}

// ---------------- flash attention (R6 structure — proven best, 50.6us) ------
// 1024 blocks: bh = bid&31, qblk = 31-(bid>>5) (heavy-first; HW backfill
// self-balances: 768 resident + 256 light backfill). One 64-row q-block per
// block, qblk+1 kv-tiles. 4 waves x 16 q-rows, 3 blocks/CU. Counted-vmcnt
// 2-phase pipeline; XOR-swizzled K/V; swapped QK^T; O^T accumulation;
// l-sum reduction after PV.
#define KPAD 72

__launch_bounds__(256, 3)
__global__ void attn_fwd(const bf16* __restrict__ Qb, const bf16* __restrict__ Kb,
                         const bf16* __restrict__ Vtb, bf16* __restrict__ Yb) {
  __shared__ bf16 Ks[2][4096];     // [buf][64 kv x 64 d] swizzled
  __shared__ bf16 Vs[2][4096];     // [buf][64 d x 64 kv] swizzled
  __shared__ bf16 Ps[4][16 * KPAD];

  const int tid  = threadIdx.x;
  const int lane = tid & 63;
  const int wv   = tid >> 6;       // 0..3
  const int lg   = lane >> 4;
  const int lc   = lane & 15;
  const int bh   = blockIdx.x & 31;
  const int qblk = 31 - (blockIdx.x >> 5);   // heavy blocks dispatch first
  const int q0   = qblk * 64;
  const int NT   = qblk + 1;

  const bf16* Qg = Qb  + (size_t)bh * TT * HD;
  const bf16* Kg = Kb  + (size_t)bh * TT * HD;
  const bf16* Vg = Vtb + (size_t)bh * HD * TT;

  const bf16x8 qf0 = *reinterpret_cast<const bf16x8*>(
      Qg + (size_t)(q0 + wv * 16 + lc) * HD + 0  + lg * 8);
  const bf16x8 qf1 = *reinterpret_cast<const bf16x8*>(
      Qg + (size_t)(q0 + wv * 16 + lc) * HD + 32 + lg * 8);

  int dstb[2], koff[2], voff[2];
#pragma unroll
  for (int c = 0; c < 2; ++c) {
    const int base = (wv * 2 + c) * 1024;
    const int lin  = base + lane * 16;
    dstb[c] = base;
    koff[c] = swzb(lin);
    voff[c] = (lin >> 7) * (TT * 2) + (swzb(lin) & 127);
  }

  auto STAGE = [&](int b, int kv) {
#pragma unroll
    for (int c = 0; c < 2; ++c) {
      gload_lds16((const bf16*)((const char*)Kg + (size_t)kv * 8192 + koff[c]),
                  (bf16*)((char*)Ks[b] + dstb[c]));
      gload_lds16((const bf16*)((const char*)Vg + (size_t)kv * 128 + voff[c]),
                  (bf16*)((char*)Vs[b] + dstb[c]));
    }
  };

  f32x4 o[4] = {};                 // O^T: o[df] row d = df*16+lg*4+r, col q = lc
  float m_run = -INFINITY, l_run = 0.f;
  bf16* Pw = Ps[wv];
  const int b_ = bh >> 4, h_ = bh & 15;
  const int qw = q0 + wv * 16;

  STAGE(0, 0);

  int cur = 0;
  for (int ti = 0; ti < NT; ++ti) {
    const int k0 = ti * 64;

    if (ti + 1 < NT) {
      STAGE(cur ^ 1, ti + 1);
      asm volatile("s_waitcnt vmcnt(4)" ::: "memory");
    } else {
      asm volatile("s_waitcnt vmcnt(0)" ::: "memory");
    }
    __builtin_amdgcn_s_barrier();
    __builtin_amdgcn_sched_barrier(0);

    const char* ksb = (const char*)Ks[cur];
    const char* vsb = (const char*)Vs[cur];

    f32x4 s[4] = {};
    __builtin_amdgcn_s_setprio(1);
#pragma unroll
    for (int kvf = 0; kvf < 4; ++kvf) {
      const bf16x8 k0f = *reinterpret_cast<const bf16x8*>(
          ksb + swzb((kvf * 16 + lc) * 128 + lg * 16));
      s[kvf] = __builtin_amdgcn_mfma_f32_16x16x32_bf16(k0f, qf0, s[kvf], 0, 0, 0);
      const bf16x8 k1f = *reinterpret_cast<const bf16x8*>(
          ksb + swzb((kvf * 16 + lc) * 128 + 64 + lg * 16));
      s[kvf] = __builtin_amdgcn_mfma_f32_16x16x32_bf16(k1f, qf1, s[kvf], 0, 0, 0);
    }
    __builtin_amdgcn_s_setprio(0);

    if (k0 + 63 > qw) {
      const int q = qw + lc;
#pragma unroll
      for (int kvf = 0; kvf < 4; ++kvf)
#pragma unroll
        for (int r = 0; r < 4; ++r)
          if (k0 + kvf * 16 + lg * 4 + r > q) s[kvf][r] = -INFINITY;
    }

    float t0 = fmaxf(fmaxf(s[0][0], s[0][1]), fmaxf(s[0][2], s[0][3]));
    float t1 = fmaxf(fmaxf(s[1][0], s[1][1]), fmaxf(s[1][2], s[1][3]));
    float t2 = fmaxf(fmaxf(s[2][0], s[2][1]), fmaxf(s[2][2], s[2][3]));
    float t3 = fmaxf(fmaxf(s[3][0], s[3][1]), fmaxf(s[3][2], s[3][3]));
    float rmax = fmaxf(fmaxf(t0, t1), fmaxf(t2, t3));
    rmax = fmaxf(rmax, __shfl_xor(rmax, 16));
    rmax = fmaxf(rmax, __shfl_xor(rmax, 32));

    const float mn = fmaxf(m_run, rmax);
    const float alpha = __builtin_amdgcn_exp2f(m_run - mn);
    m_run = mn;

#pragma unroll
    for (int kvf = 0; kvf < 4; ++kvf)
#pragma unroll
      for (int r = 0; r < 4; ++r)
        s[kvf][r] = __builtin_amdgcn_exp2f(s[kvf][r] - mn);

#pragma unroll
    for (int df = 0; df < 4; ++df)
#pragma unroll
      for (int r = 0; r < 4; ++r) o[df][r] *= alpha;

#pragma unroll
    for (int kvf = 0; kvf < 4; ++kvf) {
      bf16x4 pk = { (bf16)s[kvf][0], (bf16)s[kvf][1],
                    (bf16)s[kvf][2], (bf16)s[kvf][3] };
      *reinterpret_cast<bf16x4*>(&Pw[lc * KPAD + kvf * 16 + lg * 4]) = pk;
    }

    __builtin_amdgcn_s_setprio(1);
#pragma unroll
    for (int ks = 0; ks < 2; ++ks) {
      const bf16x8 pf = *reinterpret_cast<const bf16x8*>(
          &Pw[lc * KPAD + ks * 32 + lg * 8]);
#pragma unroll
      for (int df = 0; df < 4; ++df) {
        const bf16x8 vf = *reinterpret_cast<const bf16x8*>(
            vsb + swzb((df * 16 + lc) * 128 + ks * 64 + lg * 16));
        o[df] = __builtin_amdgcn_mfma_f32_16x16x32_bf16(vf, pf, o[df], 0, 0, 0);
      }
    }
    __builtin_amdgcn_s_setprio(0);

    float u0 = (s[0][0] + s[0][1]) + (s[0][2] + s[0][3]);
    float u1 = (s[1][0] + s[1][1]) + (s[1][2] + s[1][3]);
    float u2 = (s[2][0] + s[2][1]) + (s[2][2] + s[2][3]);
    float u3 = (s[3][0] + s[3][1]) + (s[3][2] + s[3][3]);
    float rsum = (u0 + u1) + (u2 + u3);
    rsum += __shfl_xor(rsum, 16);
    rsum += __shfl_xor(rsum, 32);
    l_run = l_run * alpha + rsum;

    __builtin_amdgcn_s_barrier();
    cur ^= 1;
  }

  {
    const float linv = 1.f / fmaxf(l_run, 1e-9f);
    const int q = qw + lc;
#pragma unroll
    for (int df = 0; df < 4; ++df) {
      bf16x4 yv = { (bf16)(o[df][0] * linv), (bf16)(o[df][1] * linv),
                    (bf16)(o[df][2] * linv), (bf16)(o[df][3] * linv) };
      *reinterpret_cast<bf16x4*>(
          Yb + ((size_t)(b_ * TT + q)) * DM + h_ * HD + df * 16 + lg * 4) = yv;
    }
  }
}

// ---------------- output projection: 64x128 tile, BK=64, swizzled LDS -------
// 16 K-steps (was 32): halves barrier-pairs, 16 MFMA/step. LDS rows are
// 128B -> T2 XOR swizzle (linear gload_lds dest + pre-swizzled global src +
// swizzled ds_read) kills the 16-way conflict. 48KB LDS, 2 blocks/CU.
__launch_bounds__(256, 2)
__global__ void gemm_out(const bf16* __restrict__ Y, const bf16* __restrict__ Wo,
                         float* __restrict__ Out) {
  __shared__ bf16 As[2][64 * 64];    // [buf][64 rows][64 el] swizzled (8KB)
  __shared__ bf16 Bs[2][128 * 64];   // [buf][128 rows][64 el] swizzled (16KB)
  const int tid  = threadIdx.x;
  const int lane = tid & 63;
  const int wv   = tid >> 6;
  const int lg   = lane >> 4, lc = lane & 15;
  const int m0   = blockIdx.x * 64;
  const int n0   = blockIdx.y * 128;
  const int wm = wv >> 1, wn = wv & 1;   // wave tile: 32 rows x 64 cols

  // staging geometry: A 2 issues, B 4 issues per thread (16B each)
  int arow[2], acol[2], adst[2];
#pragma unroll
  for (int c = 0; c < 2; ++c) {
    const int lin = c * 4096 + tid * 16;       // dest byte (linear)
    arow[c] = lin >> 7;                        // tile row
    acol[c] = (swzb(lin) & 127) >> 1;          // pre-swizzled col (elements)
    adst[c] = c * 4096 + wv * 1024;            // wave-uniform dest base
  }
  int brow[4], bcol[4], bdst[4];
#pragma unroll
  for (int c = 0; c < 4; ++c) {
    const int lin = c * 4096 + tid * 16;
    brow[c] = lin >> 7;
    bcol[c] = (swzb(lin) & 127) >> 1;
    bdst[c] = c * 4096 + wv * 1024;
  }

#define OSTAGE(buf, kt)                                                        \
  {                                                                            \
    _Pragma("unroll")                                                          \
    for (int c = 0; c < 2; ++c)                                                \
      gload_lds16(Y + (size_t)(m0 + arow[c]) * DM + (kt) * 64 + acol[c],       \
                  (bf16*)((char*)As[buf] + adst[c]));                          \
    _Pragma("unroll")                                                          \
    for (int c = 0; c < 4; ++c)                                                \
      gload_lds16(Wo + (size_t)(n0 + brow[c]) * DM + (kt) * 64 + bcol[c],      \
                  (bf16*)((char*)Bs[buf] + bdst[c]));                          \
  }

  f32x4 acc[2][4] = {};
  OSTAGE(0, 0);

  int cur = 0;
  for (int kt = 0; kt < 16; ++kt) {
    if (kt + 1 < 16) {
      OSTAGE(cur ^ 1, kt + 1);
      asm volatile("s_waitcnt vmcnt(6)" ::: "memory");
    } else {
      asm volatile("s_waitcnt vmcnt(0)" ::: "memory");
    }
    __builtin_amdgcn_s_barrier();
    __builtin_amdgcn_sched_barrier(0);

    const char* asb = (const char*)As[cur];
    const char* bsb = (const char*)Bs[cur];
#pragma unroll
    for (int ks = 0; ks < 2; ++ks) {
      bf16x8 a[2], b[4];
#pragma unroll
      for (int i = 0; i < 2; ++i) {
        const int r = wm * 32 + i * 16 + lc;
        a[i] = *reinterpret_cast<const bf16x8*>(
            asb + r * 128 + ((ks * 64 + lg * 16) ^ ((r & 7) << 4)));
      }
#pragma unroll
      for (int j = 0; j < 4; ++j) {
        const int r = wn * 64 + j * 16 + lc;
        b[j] = *reinterpret_cast<const bf16x8*>(
            bsb + r * 128 + ((ks * 64 + lg * 16) ^ ((r & 7) << 4)));
      }
      __builtin_amdgcn_s_setprio(1);
#pragma unroll
      for (int i = 0; i < 2; ++i)
#pragma unroll
        for (int j = 0; j < 4; ++j)
          acc[i][j] = __builtin_amdgcn_mfma_f32_16x16x32_bf16(a[i], b[j], acc[i][j], 0, 0, 0);
      __builtin_amdgcn_s_setprio(0);
    }

    __builtin_amdgcn_s_barrier();
    cur ^= 1;
  }
#undef OSTAGE

#pragma unroll
  for (int i = 0; i < 2; ++i) {
    const int mg = m0 + wm * 32 + i * 16 + lg * 4;
#pragma unroll
    for (int j = 0; j < 4; ++j) {
      const int n = n0 + wn * 64 + j * 16 + lc;
#pragma unroll
      for (int r = 0; r < 4; ++r)
        Out[(size_t)(mg + r) * DM + n] = acc[i][j][r];
    }
  }
}

extern "C" void kernel_launch(void* const* d_in, const int* in_sizes, int n_in,
                              void* d_out, int out_size, void* d_ws, size_t ws_size,
                              hipStream_t stream) {
  const float* x  = (const float*)d_in[0];
  const float* Wq = (const float*)d_in[1];
  const float* Wk = (const float*)d_in[2];
  const float* Wv = (const float*)d_in[3];
  const float* Wo = (const float*)d_in[4];
  float* out = (float*)d_out;
  char* ws = (char*)d_ws;
  const size_t MB = 1024 * 1024;

  bf16* xb  = (bf16*)(ws + 0);        // 8 MB, reused as yb after QKV GEMM
  bf16* wqb = (bf16*)(ws + 8  * MB);
  bf16* wkb = (bf16*)(ws + 10 * MB);
  bf16* wvb = (bf16*)(ws + 12 * MB);
  bf16* wob = (bf16*)(ws + 14 * MB);
  bf16* Qb  = (bf16*)(ws + 16 * MB);  // [32,2048,64]
  bf16* Kb  = (bf16*)(ws + 24 * MB);
  bf16* Vtb = (bf16*)(ws + 32 * MB);  // [32,64,2048]
  bf16* yb  = xb;

  cvt_all<<<8192, 256, 0, stream>>>(x, Wq, Wk, Wv, Wo, xb, wqb, wkb, wvb, wob);
  gemm_qkv<<<dim3(32, 24), 256, 0, stream>>>(xb, wqb, wkb, wvb, Qb, Kb, Vtb);
  attn_fwd<<<1024, 256, 0, stream>>>(Qb, Kb, Vtb, yb);
  gemm_out<<<dim3(64, 8), 256, 0, stream>>>(yb, wob, out);
}